// Round 9
// baseline (124.164 us; speedup 1.0000x reference)
//
#include <hip/hip_runtime.h>
#include <cstdint>
#include <cstddef>

using f16   = _Float16;
using half8 = __attribute__((ext_vector_type(8))) _Float16;
using f32x4 = __attribute__((ext_vector_type(4))) float;
using ull   = unsigned long long;

#define DINL __device__ __forceinline__

// global -> LDS async, 16B per lane. LDS dest wave-uniform base + lane*16.
DINL void gload_lds16(const void* gptr, void* lptr) {
  __builtin_amdgcn_global_load_lds(
      reinterpret_cast<const __attribute__((address_space(1))) uint32_t*>(
          reinterpret_cast<uintptr_t>(gptr)),
      reinterpret_cast<__attribute__((address_space(3))) uint32_t*>(
          reinterpret_cast<uintptr_t>(lptr)),
      16, 0, 0);
}

DINL unsigned pkh(float a, float b) {
  unsigned short ha = __builtin_bit_cast(unsigned short, (f16)a);
  unsigned short hb = __builtin_bit_cast(unsigned short, (f16)b);
  return (unsigned)ha | ((unsigned)hb << 16);
}

struct U4 { unsigned x, y, z, w; };

// x -> 16B A-row: [B0..B5 uniform cubic B-spline, silu(x), 0] as 8 f16.
// Funnel-shift placement; validated rounds 5-8 (absmax 0.03125).
DINL U4 expand_pack(float x) {
  float xs = (x + 3.0f) * 1.5f;
  float mf = floorf(xs);
  int   m  = (int)mf;
  float u = xs - mf, u2 = u * u, u3 = u2 * u, um = 1.0f - u;
  float p3 = u3 * (1.0f / 6.0f);
  float p2 = (1.0f + 3.0f * (u + u2 - u3)) * (1.0f / 6.0f);
  float p1 = (4.0f - 6.0f * u2 + 3.0f * u3) * (1.0f / 6.0f);
  float p0 = um * um * um * (1.0f / 6.0f);
  ull P = (ull)pkh(p0, p1) | ((ull)pkh(p2, p3) << 32);
  if ((unsigned)m > 8u) P = 0;
  int s    = m * 16 - 48;
  int sneg = min(63, max(0, -s));
  int spos = min(63, max(0, s));
  int shi2 = min(63, max(0, s - 64));
  ull rlo = (s < 0) ? (P >> sneg) : ((s < 64) ? (P << spos) : 0ull);
  ull rhi = (s < 0) ? 0ull
                    : ((s < 64) ? ((P >> (63 - spos)) >> 1) : (P << shi2));
  float sil = x / (1.0f + __expf(-x));
  U4 r;
  r.x = (unsigned)rlo;
  r.y = (unsigned)(rlo >> 32);
  r.z = (unsigned)rhi;
  r.w = pkh(sil, 0.0f);
  return r;
}

// Weight prep, PRE-SWIZZLED (rule 21): dim slot stored at (d&7)^(n&7) so a
// linear global_load_lds yields the swizzled LDS tile. Validated rounds 2-8.
__global__ __launch_bounds__(256)
void prep_w_kernel(const float* __restrict__ coef, const float* __restrict__ ssp,
                   const float* __restrict__ sb, f16* __restrict__ Wt,
                   int Din, int Dout) {
  int idx = blockIdx.x * 256 + threadIdx.x;
  if (idx >= Din * Dout) return;
  int n = idx / Din;
  int d = idx - n * Din;
  float s = ssp[(size_t)d * Dout + n];
  const float* c = coef + ((size_t)d * Dout + n) * 6;
  half8 wv;
#pragma unroll
  for (int b = 0; b < 6; ++b) wv[b] = (f16)(c[b] * s);
  wv[6] = (f16)sb[(size_t)d * Dout + n];
  wv[7] = (f16)0.0f;
  int dp = (d & ~7) | ((d & 7) ^ (n & 7));
  *reinterpret_cast<half8*>(Wt + ((size_t)n * Din + dp) * 8) = wv;
}

// ---------------------------------------------------------------------------
// Fused KAN GEMM v9: v8 structure (PASSED, absmax 0.03125) with two changes:
//  (1) ALL x floats (NS=32 per thread) preloaded to registers at prologue ->
//      no VMEM x-load outstanding at any steady-state barrier (the v8 barrier
//      implicitly vmcnt(0)-drained the same-step x prefetch = exposed HBM
//      latency every step). Only the 4 L2-resident B gloads drain per step.
//  (2) K-loop fully unrolled (template<NS>): xs[] statically indexed (no
//      scratch), stageB global offsets become base+imm (<=3968B, fits 13-bit).
// BM=64 x BN=256, 8 waves (2x4), BK=64, static 80KB LDS, 2 blocks/CU.
// ---------------------------------------------------------------------------
template <bool BIAS, int NS>
__global__ __launch_bounds__(512, 4)
void kan_gemm(const float* __restrict__ X, int ldx,
              const f16* __restrict__ Wt, int ldw,
              const float* __restrict__ nscale, const float* __restrict__ nbias,
              int N, float* __restrict__ Out) {
  __shared__ alignas(16) f16 A0[64 * 64];      //  8 KB
  __shared__ alignas(16) f16 A1[64 * 64];      //  8 KB
  __shared__ alignas(16) f16 B0[256 * 64];     // 32 KB
  __shared__ alignas(16) f16 B1[256 * 64];     // 32 KB

  const int tid  = threadIdx.x;
  const int w    = tid >> 6;
  const int lane = tid & 63;
  const int l15  = lane & 15, l7 = lane & 7, hi = lane >> 4;
  const int wm   = w >> 2, wn = w & 3;         // wave grid 2 x 4
  const int m0   = blockIdx.y * 64;
  const int n0   = blockIdx.x * 256;
  const int dim0 = blockIdx.z * (NS * 8);      // split-K dim offset
  float* outz = Out + (size_t)blockIdx.z * ((size_t)gridDim.y * 64) * N;

  // A: 1 element/thread/step (64 rows x 8 dims = 512)
  const int ar = tid >> 3, ad = tid & 7;
  const float* asrc = X + (size_t)(m0 + ar) * ldx + dim0 + ad;
  const int aoff = ar * 64 + 8 * (ad ^ (ar & 7));

  // preload ALL x floats for this thread (32B stride; block panel = 64KB,
  // every fetched line fully used across threads)
  float xs[NS];
#pragma unroll
  for (int s = 0; s < NS; ++s) xs[s] = asrc[s * 8];

  // B: 4 x 16B chunks/thread (256 rows x 8 slots = 2048 chunks)
  const f16* wb[4];
  int ldsb[4];
#pragma unroll
  for (int q = 0; q < 4; ++q) {
    int c   = tid + q * 512;
    wb[q]   = Wt + (size_t)(n0 + (c >> 3)) * ldw + (size_t)dim0 * 8 + (c & 7) * 8;
    ldsb[q] = c * 8;
  }

  f32x4 acc[2][4] = {};

  auto stageB = [&](f16* buf, int k0) {
#pragma unroll
    for (int q = 0; q < 4; ++q) gload_lds16(wb[q] + k0, buf + ldsb[q]);
  };

  auto compute = [&](const f16* bA, const f16* bB) {
#pragma unroll
    for (int kk = 0; kk < 2; ++kk) {
      const int sl = kk * 4 + hi;
      half8 av[2], bv[4];
#pragma unroll
      for (int i = 0; i < 2; ++i)
        av[i] = *reinterpret_cast<const half8*>(
            bA + (wm * 32 + i * 16 + l15) * 64 + 8 * (sl ^ l7));
#pragma unroll
      for (int j = 0; j < 4; ++j)
        bv[j] = *reinterpret_cast<const half8*>(
            bB + (wn * 64 + j * 16 + l15) * 64 + 8 * (sl ^ l7));
#pragma unroll
      for (int i = 0; i < 2; ++i)
#pragma unroll
        for (int j = 0; j < 4; ++j)
          acc[i][j] = __builtin_amdgcn_mfma_f32_16x16x32_f16(av[i], bv[j], acc[i][j], 0, 0, 0);
    }
  };

  auto writeA = [&](f16* buf, U4 e) {
    *reinterpret_cast<U4*>(buf + aoff) = e;
  };

  // ---- prologue: tile 0 in A0/B0 (one-time full drain at first barrier) ----
  stageB(B0, 0);
  writeA(A0, expand_pack(xs[0]));
  __syncthreads();

  // ---- steady state: fully unrolled, 2 tiles per pair ----
#pragma unroll
  for (int p = 0; p <= NS / 2 - 2; ++p) {
    // half A: compute tile 2p; stage B(2p+1); expand x(2p+1)
    stageB(B1, (2 * p + 1) * 64);
    compute(A0, B0);
    writeA(A1, expand_pack(xs[2 * p + 1]));
    __syncthreads();
    // half B: compute tile 2p+1; stage B(2p+2); expand x(2p+2)
    stageB(B0, (2 * p + 2) * 64);
    compute(A1, B1);
    writeA(A0, expand_pack(xs[2 * p + 2]));
    __syncthreads();
  }

  // ---- tail: tiles NS-2 (A0/B0) and NS-1 (A1/B1) ----
  stageB(B1, (NS - 1) * 64);
  compute(A0, B0);
  writeA(A1, expand_pack(xs[NS - 1]));
  __syncthreads();
  compute(A1, B1);

  // ---- epilogue: Out = ns*acc (+ nb) ----
#pragma unroll
  for (int j = 0; j < 4; ++j) {
    int col   = n0 + wn * 64 + j * 16 + l15;
    float nsv = nscale[col];
    float nbv = BIAS ? nbias[col] : 0.0f;
#pragma unroll
    for (int i = 0; i < 2; ++i) {
      int rb = m0 + wm * 32 + i * 16 + hi * 4;
#pragma unroll
      for (int r = 0; r < 4; ++r)
        outz[(size_t)(rb + r) * N + col] = nsv * acc[i][j][r] + nbv;
    }
  }
}

// ---------------------------------------------------------------------------
// partial0 + partial1 + node_bias2 + residual -> LayerNorm(256) -> exact GELU
// ---------------------------------------------------------------------------
__global__ __launch_bounds__(256)
void ln_gelu_kernel(const float* __restrict__ P0, const float* __restrict__ P1,
                    const float* __restrict__ X,  const float* __restrict__ nb2,
                    const float* __restrict__ gamma, const float* __restrict__ beta,
                    float* __restrict__ out, int rows) {
  int row  = blockIdx.x * 4 + (threadIdx.x >> 6);
  int lane = threadIdx.x & 63;
  if (row >= rows) return;
  const float4 a  = *reinterpret_cast<const float4*>(P0 + (size_t)row * 256 + lane * 4);
  const float4 b  = *reinterpret_cast<const float4*>(P1 + (size_t)row * 256 + lane * 4);
  const float4 xr = *reinterpret_cast<const float4*>(X  + (size_t)row * 256 + lane * 4);
  const float4 nb = *reinterpret_cast<const float4*>(nb2 + lane * 4);
  const float4 g  = *reinterpret_cast<const float4*>(gamma + lane * 4);
  const float4 be = *reinterpret_cast<const float4*>(beta + lane * 4);
  float h[4] = { a.x + b.x + nb.x + xr.x, a.y + b.y + nb.y + xr.y,
                 a.z + b.z + nb.z + xr.z, a.w + b.w + nb.w + xr.w };
  float s = h[0] + h[1] + h[2] + h[3];
#pragma unroll
  for (int o = 32; o >= 1; o >>= 1) s += __shfl_xor(s, o);
  float mu = s * (1.0f / 256.0f);
  float vs = 0.f;
#pragma unroll
  for (int j = 0; j < 4; ++j) { float d = h[j] - mu; vs += d * d; }
#pragma unroll
  for (int o = 32; o >= 1; o >>= 1) vs += __shfl_xor(vs, o);
  float inv = rsqrtf(vs * (1.0f / 256.0f) + 1e-5f);
  float o4[4];
#pragma unroll
  for (int j = 0; j < 4; ++j) {
    float gj = (&g.x)[j], bj = (&be.x)[j];
    float v = (h[j] - mu) * inv * gj + bj;
    o4[j] = 0.5f * v * (1.0f + erff(v * 0.70710678118654752f));
  }
  *reinterpret_cast<float4*>(out + (size_t)row * 256 + lane * 4) =
      make_float4(o4[0], o4[1], o4[2], o4[3]);
}

// ---------------------------------------------------------------------------
extern "C" void kernel_launch(void* const* d_in, const int* in_sizes, int n_in,
                              void* d_out, int out_size, void* d_ws, size_t ws_size,
                              hipStream_t stream) {
  (void)in_sizes; (void)n_in; (void)out_size; (void)ws_size;
  const float* x     = (const float*)d_in[0];
  const float* coef1 = (const float*)d_in[2];
  const float* sb1   = (const float*)d_in[3];
  const float* ssp1  = (const float*)d_in[4];
  const float* ns1   = (const float*)d_in[5];
  const float* nb1   = (const float*)d_in[6];
  const float* coef2 = (const float*)d_in[8];
  const float* sb2   = (const float*)d_in[9];
  const float* ssp2  = (const float*)d_in[10];
  const float* ns2   = (const float*)d_in[11];
  const float* nb2   = (const float*)d_in[12];
  const float* lgam  = (const float*)d_in[13];
  const float* lbet  = (const float*)d_in[14];
  float* out = (float*)d_out;

  const int Ntok = 16 * 1024;
  const int D0 = 256, D1 = 512, D2 = 256;

  // ws: h1 [Ntok,512] f32 | part [2][Ntok,256] f32 | Wt1 2MB | Wt2 2MB
  char*  ws   = (char*)d_ws;
  float* h1   = (float*)ws;
  size_t off  = (size_t)Ntok * D1 * sizeof(float);
  float* part = (float*)(ws + off);
  off += (size_t)2 * Ntok * D2 * sizeof(float);
  f16* Wt1 = (f16*)(ws + off);
  off += (size_t)D1 * D0 * 8 * sizeof(f16);
  f16* Wt2 = (f16*)(ws + off);

  prep_w_kernel<<<(D0 * D1 + 255) / 256, 256, 0, stream>>>(coef1, ssp1, sb1, Wt1, D0, D1);
  prep_w_kernel<<<(D1 * D2 + 255) / 256, 256, 0, stream>>>(coef2, ssp2, sb2, Wt2, D1, D2);

  // layer 1: [16384 x 2048] x [512 x 2048]^T -> h1. 2 n-panels x 256 m = 512 blocks.
  kan_gemm<true, 32><<<dim3(D1 / 256, Ntok / 64, 1), 512, 0, stream>>>(
      x, D0, Wt1, D0 * 8, ns1, nb1, D1, h1);

  // layer 2: full-width N=256, split-K=2 -> 512 blocks; partials ns2*acc.
  kan_gemm<false, 32><<<dim3(D2 / 256, Ntok / 64, 2), 512, 0, stream>>>(
      h1, D1, Wt2, D1 * 8, ns2, nullptr, D2, part);

  // reduce partials + bias + residual + LN + GELU
  ln_gelu_kernel<<<Ntok / 4, 256, 0, stream>>>(
      part, part + (size_t)Ntok * D2, x, nb2, lgam, lbet, out, Ntok);
}